// Round 5
// baseline (661.619 us; speedup 1.0000x reference)
//
#include <hip/hip_runtime.h>
#include <stdint.h>

// Problem constants
#define BROWS 16384
#define FDIM  2048
#define NCLS  14
#define ADIM  64
#define NCAT  2176   // 2048 (W_proj) + 14 (W_fc) + 114 zero pad -> 17 tiles of 128
#define QKN   1792   // 2*C*D

typedef __attribute__((ext_vector_type(8))) short bhalf8_t;   // 8 bf16 (4 VGPRs)
typedef __attribute__((ext_vector_type(4))) float f32x4_t;    // MFMA C/D frag

__device__ __forceinline__ unsigned short f2bf(float f) {
  unsigned int u = __builtin_bit_cast(unsigned int, f);
  u += 0x7fffu + ((u >> 16) & 1u);      // RNE
  return (unsigned short)(u >> 16);
}
__device__ __forceinline__ float bf2f(unsigned short s) {
  return __builtin_bit_cast(float, (unsigned int)s << 16);
}

__device__ __forceinline__ void gl_lds16(const void* g, void* l) {
  __builtin_amdgcn_global_load_lds(
      (const __attribute__((address_space(1))) unsigned int*)g,
      (__attribute__((address_space(3))) unsigned int*)l, 16, 0, 0);
}

__device__ __forceinline__ bhalf8_t cvt8(float4 a, float4 b) {
  bhalf8_t o;
  o[0] = f2bf(a.x); o[1] = f2bf(a.y); o[2] = f2bf(a.z); o[3] = f2bf(a.w);
  o[4] = f2bf(b.x); o[5] = f2bf(b.y); o[6] = f2bf(b.z); o[7] = f2bf(b.w);
  return o;
}

// ---------------- fused prep: feature cast | W_cat build | W_qk cast | stats zero ----
// One launch replaces 3 casts + memset (R4 post-mortem: ~10us/launch overhead).
#define PB_FEAT 16384              // blocks 0..16383: features -> bf16 (8/thread)
#define PB_WCAT (PB_FEAT + NCAT)   // blocks 16384..18559: W_cat rows
#define PB_WQK  (PB_WCAT + 1792)   // blocks 18560..20351: W_qk cast
#define PB_TOT  (PB_WQK + 1)       // last block: zero colsum/colsq
__global__ void prep(const float* __restrict__ features,
                     const float* __restrict__ Wp, const float* __restrict__ Wf,
                     const float* __restrict__ Wqk,
                     unsigned short* __restrict__ featC,
                     unsigned short* __restrict__ WcatC,
                     unsigned short* __restrict__ WqkC,
                     float* __restrict__ stats) {
  int b = blockIdx.x;
  if (b < PB_FEAT) {
    int t = b * 256 + threadIdx.x;
    const float4* s = (const float4*)features + 2 * (size_t)t;
    *((bhalf8_t*)featC + t) = cvt8(s[0], s[1]);
  } else if (b < PB_WCAT) {
    int row = b - PB_FEAT;
    int c8 = threadIdx.x * 8;
    const float* src = nullptr;
    if (row < 2048) src = Wp + (size_t)row * FDIM + c8;
    else if (row < 2048 + NCLS) src = Wf + (size_t)(row - 2048) * FDIM + c8;
    bhalf8_t o = {0,0,0,0,0,0,0,0};
    if (src) o = cvt8(*(const float4*)src, *(const float4*)(src + 4));
    *(bhalf8_t*)(WcatC + (size_t)row * FDIM + c8) = o;
  } else if (b < PB_WQK) {
    int t = (b - PB_WCAT) * 256 + threadIdx.x;
    const float4* s = (const float4*)Wqk + 2 * (size_t)t;
    *((bhalf8_t*)WqkC + t) = cvt8(s[0], s[1]);
  } else {
    float4 z = {0.f, 0.f, 0.f, 0.f};
#pragma unroll
    for (int i = 0; i < 4; ++i)
      ((float4*)stats)[threadIdx.x * 4 + i] = z;   // 4096 floats = colsum+colsq
  }
}

// ---------------- MFMA GEMM: fp32 out, direct stores (R1's proven-fast epilogue) ----
// 128x128 tile, BK=64, 256 threads (4 waves 2x2), 16x16x32 bf16 MFMA.
// K-loop LDS: row = 8 chunks of 16B; chunk at slot (chunk ^ (row&7)) -> conflict-free
// ds_read_b128 while keeping global_load_lds destinations contiguous.
// Epilogue: fp32 direct global_store_dword (64B segments, fire-and-forget). Measured
// R1-R4: this beats bf16 in-GEMM stores — the LDS-transpose staged store costs
// ~40us/GEMM (64 scalar ds_write_b16 + 3 barriers + VGPR 80->92) vs ~25us of extra
// HBM traffic for fp32.
// MODE 0 (GEMM1): fp32 h[B,2048] (+bias bp); col-block 16 -> fp32 logits[B,16] (+bfc).
// MODE 1 (GEMM2): plain fp32 store.
template<int MODE>
__global__ __launch_bounds__(256) void gemm_bt(
    const unsigned short* __restrict__ A, const unsigned short* __restrict__ Bw,
    const float* __restrict__ bp, const float* __restrict__ bfc,
    float* __restrict__ C, float* __restrict__ logits,
    int K, int lda, int ldb, int ldc)
{
  __shared__ unsigned short lA[128 * 64];
  __shared__ unsigned short lB[128 * 64];
  const int tid = threadIdx.x;
  const int lane = tid & 63, wv = tid >> 6;
  const int m = lane & 15, quad = lane >> 4;
  const size_t rowBase = (size_t)blockIdx.x * 128;
  const size_t colBase = (size_t)blockIdx.y * 128;
  const int m0 = (wv >> 1) * 64, n0 = (wv & 1) * 64;

  f32x4_t acc[4][4];
#pragma unroll
  for (int i = 0; i < 4; ++i)
#pragma unroll
    for (int j = 0; j < 4; ++j) acc[i][j] = (f32x4_t){0.f, 0.f, 0.f, 0.f};

  int sS[4];                 // 16B slot index in LDS tile
  size_t gA[4], gB[4];       // element offsets of the staged chunk
#pragma unroll
  for (int i = 0; i < 4; ++i) {
    int s = ((i * 4 + wv) << 6) + lane;   // [0,1024): 4 issues x 4 waves x 64 lanes
    int r = s >> 3, qp = s & 7;
    int q = qp ^ (r & 7);                 // global k-chunk held at slot qp
    sS[i] = s;
    gA[i] = (rowBase + r) * (size_t)lda + q * 8;
    gB[i] = (colBase + r) * (size_t)ldb + q * 8;
  }

  for (int kb = 0; kb < K; kb += 64) {
#pragma unroll
    for (int i = 0; i < 4; ++i) {
      gl_lds16(A + gA[i] + kb, &lA[sS[i] * 8]);
      gl_lds16(Bw + gB[i] + kb, &lB[sS[i] * 8]);
    }
    __syncthreads();   // drains vmcnt before barrier
#pragma unroll
    for (int ks = 0; ks < 2; ++ks) {
      const int qc = ks * 4 + quad;       // k-chunk this lane's fragment needs
      bhalf8_t af[4], bf[4];
#pragma unroll
      for (int mi = 0; mi < 4; ++mi) {
        int r = m0 + mi * 16 + m;
        af[mi] = *(const bhalf8_t*)&lA[(r * 8 + (qc ^ (r & 7))) * 8];
      }
#pragma unroll
      for (int ni = 0; ni < 4; ++ni) {
        int r = n0 + ni * 16 + m;
        bf[ni] = *(const bhalf8_t*)&lB[(r * 8 + (qc ^ (r & 7))) * 8];
      }
#pragma unroll
      for (int mi = 0; mi < 4; ++mi)
#pragma unroll
        for (int ni = 0; ni < 4; ++ni)
          acc[mi][ni] = __builtin_amdgcn_mfma_f32_16x16x32_bf16(af[mi], bf[ni], acc[mi][ni], 0, 0, 0);
    }
    __syncthreads();
  }

  // ---- epilogue ---- (C/D layout: col = lane&15, row = quad*4 + reg)
  if (MODE == 0 && colBase >= 2048) {
    // logits tile (block-uniform branch): rel cols 0..15 only, direct fp32 store
    if (n0 == 0) {
      float bv = (m < NCLS) ? bfc[m] : 0.f;
#pragma unroll
      for (int mi = 0; mi < 4; ++mi) {
        size_t grow = rowBase + m0 + mi * 16 + quad * 4;
#pragma unroll
        for (int r = 0; r < 4; ++r)
          logits[(grow + r) * 16 + m] = acc[mi][0][r] + bv;
      }
    }
    return;
  }

#pragma unroll
  for (int ni = 0; ni < 4; ++ni) {
    size_t gcol = colBase + n0 + ni * 16 + m;
    float bv = (MODE == 0) ? bp[gcol] : 0.f;
#pragma unroll
    for (int mi = 0; mi < 4; ++mi) {
      size_t grow = rowBase + m0 + mi * 16 + quad * 4;
#pragma unroll
      for (int r = 0; r < 4; ++r)
        C[(grow + r) * (size_t)ldc + gcol] = acc[mi][ni][r] + bv;
    }
  }
}

// ---------------- BatchNorm stats (fp32 h, 8 cols/thread, 64 row-blocks) ----------------
__global__ void bn_stats(const float* __restrict__ h,
                         float* __restrict__ cs, float* __restrict__ cq) {
  int c8 = threadIdx.x * 8;            // col group [0, 2048)
  int r0 = blockIdx.x * 256;           // gridDim.x = 64
  float s[8] = {0,0,0,0,0,0,0,0}, q[8] = {0,0,0,0,0,0,0,0};
  for (int r = 0; r < 256; ++r) {
    const float* p = h + (size_t)(r0 + r) * FDIM + c8;
    float4 a = *(const float4*)p, b = *(const float4*)(p + 4);
    float v[8] = {a.x, a.y, a.z, a.w, b.x, b.y, b.z, b.w};
#pragma unroll
    for (int j = 0; j < 8; ++j) { s[j] += v[j]; q[j] += v[j] * v[j]; }
  }
#pragma unroll
  for (int j = 0; j < 8; ++j) {
    atomicAdd(&cs[c8 + j], s[j]);
    atomicAdd(&cq[c8 + j], q[j]);
  }
}

// ---------------- BatchNorm finalize+apply: fp32 h -> bf16 hb ----------------
__global__ void bn_apply(const float* __restrict__ h, unsigned short* __restrict__ hb,
                         const float* __restrict__ cs, const float* __restrict__ cq,
                         const float* __restrict__ g, const float* __restrict__ bt) {
  int t = blockIdx.x * 256 + threadIdx.x;   // grid 16384 -> t < 4194304
  int row = t >> 8;
  int c8 = (t & 255) << 3;
  const float inv = 1.f / (float)BROWS;
  float sc[8], sh[8];
#pragma unroll
  for (int j = 0; j < 8; ++j) {
    int c = c8 + j;
    float mu = cs[c] * inv;
    float var = cq[c] * inv - mu * mu;
    float s = g[c] * rsqrtf(var + 1e-5f);
    sc[j] = s;
    sh[j] = bt[c] - mu * s;
  }
  const float* p = h + (size_t)row * FDIM + c8;
  float4 a = *(const float4*)p, b = *(const float4*)(p + 4);
  float v[8] = {a.x, a.y, a.z, a.w, b.x, b.y, b.z, b.w};
  bhalf8_t o;
#pragma unroll
  for (int j = 0; j < 8; ++j)
    o[j] = f2bf(fmaxf(v[j] * sc[j] + sh[j], 0.f));
  *(bhalf8_t*)(hb + (size_t)row * FDIM + c8) = o;
}

// ---------------- attention epilogue: one wave per row (fp32 qk, inline f2bf) --------
// attn = q k^T (14x14, K=64) via 16x16 MFMA chain; diag subtract, max-|.| normalize,
// corr = attn @ sigmoid(logits); out = logits + gamma*corr.
__global__ __launch_bounds__(256) void attn_ep(
    const float* __restrict__ qk, const float* __restrict__ logits,
    const float* __restrict__ gamma, float* __restrict__ out)
{
  const int lane = threadIdx.x & 63;
  const int wv = threadIdx.x >> 6;
  const int b = blockIdx.x * 4 + wv;
  const int m = lane & 15, quad = lane >> 4;
  const float* qrow = qk + (size_t)b * QKN;
  f32x4_t acc = (f32x4_t){0.f, 0.f, 0.f, 0.f};
#pragma unroll
  for (int ks = 0; ks < 2; ++ks) {
    bhalf8_t af = {0,0,0,0,0,0,0,0}, bf = {0,0,0,0,0,0,0,0};
    if (m < NCLS) {
      const float* qa = qrow + m * 64 + ks * 32 + quad * 8;  // q[b][m][k..k+8)
      af = cvt8(*(const float4*)qa,         *(const float4*)(qa + 4));
      bf = cvt8(*(const float4*)(qa + 896), *(const float4*)(qa + 900));  // k[b][m][...]
    }
    acc = __builtin_amdgcn_mfma_f32_16x16x32_bf16(af, bf, acc, 0, 0, 0);
  }
  // acc[r] = attn[c = quad*4+r][e = m]
  float logit_e = (m < NCLS) ? logits[(size_t)b * 16 + m] : 0.f;
  float sig = 1.f / (1.f + __expf(-logit_e));
  float corr[4];
#pragma unroll
  for (int r = 0; r < 4; ++r) {
    int c = quad * 4 + r;
    float diag = __shfl(acc[r], (lane & 48) + c, 64);  // attn[c][c] lives in same 16-lane group
    float a = acc[r] - diag;
    float av = (m < NCLS) ? fabsf(a) : 0.f;
    av = fmaxf(av, __shfl_xor(av, 1, 64));
    av = fmaxf(av, __shfl_xor(av, 2, 64));
    av = fmaxf(av, __shfl_xor(av, 4, 64));
    av = fmaxf(av, __shfl_xor(av, 8, 64));
    float v = (m < NCLS) ? (a / av) * sig : 0.f;
    v += __shfl_xor(v, 1, 64);
    v += __shfl_xor(v, 2, 64);
    v += __shfl_xor(v, 4, 64);
    v += __shfl_xor(v, 8, 64);
    corr[r] = v;
  }
  if (m == 0) {
#pragma unroll
    for (int r = 0; r < 4; ++r) {
      int c = quad * 4 + r;
      if (c < NCLS) {
        float lc = logits[(size_t)b * 16 + c];
        out[(size_t)b * NCLS + c] = lc + gamma[c] * corr[r];
      }
    }
  }
}

// ---------------- launch ----------------

extern "C" void kernel_launch(void* const* d_in, const int* in_sizes, int n_in,
                              void* d_out, int out_size, void* d_ws, size_t ws_size,
                              hipStream_t stream) {
  const float* features = (const float*)d_in[0];
  const float* W_proj   = (const float*)d_in[1];
  const float* b_proj   = (const float*)d_in[2];
  const float* bn_gamma = (const float*)d_in[3];
  const float* bn_beta  = (const float*)d_in[4];
  const float* W_qk     = (const float*)d_in[5];
  const float* gamma    = (const float*)d_in[6];
  const float* W_fc     = (const float*)d_in[7];
  const float* b_fc     = (const float*)d_in[8];
  float* out = (float*)d_out;

  char* ws = (char*)d_ws;
  unsigned short* featC   = (unsigned short*)ws;                  //  67,108,864 B (bf16 features)
  unsigned short* WcatC   = (unsigned short*)(ws + 67108864);     //   8,912,896 B
  unsigned short* WqkC    = (unsigned short*)(ws + 76021760);     //   7,340,032 B
  float*          hF      = (float*)(ws + 83361792);              // 134,217,728 B (fp32 h)
  float*          logitsB = (float*)(ws + 217579520);             //   1,048,576 B ([B,16] fp32)
  float*          colsum  = (float*)(ws + 218628096);             //       8,192 B
  float*          colsq   = (float*)(ws + 218636288);             //       8,192 B (tot 218,644,480)
  unsigned short* hb = featC;          // bf16 h: featC dead after GEMM1
  float*          qkF = hF;            // fp32 qk: hF dead after bn_apply

  // fused prep: casts + W_cat build + stats zeroing (one launch)
  prep<<<PB_TOT, 256, 0, stream>>>(features, W_proj, W_fc, W_qk,
                                   featC, WcatC, WqkC, colsum);

  // GEMM1: fp32 h[B,2048] (+bias) and fp32 logits[B,16] (+bias)
  gemm_bt<0><<<dim3(BROWS / 128, NCAT / 128), 256, 0, stream>>>(
      featC, WcatC, b_proj, b_fc, hF, logitsB, FDIM, FDIM, FDIM, FDIM);

  // BN stats over fp32 h
  bn_stats<<<64, 256, 0, stream>>>(hF, colsum, colsq);

  // BN finalize+apply (relu): fp32 h -> bf16 hb (overwrites dead featC)
  bn_apply<<<16384, 256, 0, stream>>>(hF, hb, colsum, colsq, bn_gamma, bn_beta);

  // GEMM2: fp32 qk[B,1792] = h @ W_qk^T (overwrites dead hF)
  gemm_bt<1><<<dim3(BROWS / 128, QKN / 128), 256, 0, stream>>>(
      hb, WqkC, nullptr, nullptr, qkF, nullptr, FDIM, FDIM, FDIM, QKN);

  // attention epilogue (one wave per row)
  attn_ep<<<BROWS / 4, 256, 0, stream>>>(qkF, logitsB, gamma, out);
}

// Round 6
// 647.979 us; speedup vs baseline: 1.0210x; 1.0210x over previous
//
#include <hip/hip_runtime.h>
#include <stdint.h>

// Problem constants
#define BROWS 16384
#define FDIM  2048
#define NCLS  14
#define ADIM  64
#define NCAT  2176   // 2048 (W_proj) + 14 (W_fc) + 114 zero pad -> 17 tiles of 128
#define QKN   1792   // 2*C*D

typedef __attribute__((ext_vector_type(8))) short bhalf8_t;   // 8 bf16 (4 VGPRs)
typedef __attribute__((ext_vector_type(4))) float f32x4_t;    // MFMA C/D frag

__device__ __forceinline__ unsigned short f2bf(float f) {
  unsigned int u = __builtin_bit_cast(unsigned int, f);
  u += 0x7fffu + ((u >> 16) & 1u);      // RNE
  return (unsigned short)(u >> 16);
}

__device__ __forceinline__ void gl_lds16(const void* g, void* l) {
  __builtin_amdgcn_global_load_lds(
      (const __attribute__((address_space(1))) unsigned int*)g,
      (__attribute__((address_space(3))) unsigned int*)l, 16, 0, 0);
}

__device__ __forceinline__ bhalf8_t cvt8(float4 a, float4 b) {
  bhalf8_t o;
  o[0] = f2bf(a.x); o[1] = f2bf(a.y); o[2] = f2bf(a.z); o[3] = f2bf(a.w);
  o[4] = f2bf(b.x); o[5] = f2bf(b.y); o[6] = f2bf(b.z); o[7] = f2bf(b.w);
  return o;
}

// ---------------- fused prep: feature cast | W_cat build | W_qk cast | bias | zero ----
#define PB_FEAT 16384              // blocks 0..16383: features -> bf16 (8/thread)
#define PB_WCAT (PB_FEAT + NCAT)   // next 2176: W_cat rows
#define PB_WQK  (PB_WCAT + 1792)   // next 1792: W_qk cast
#define PB_BIAS (PB_WQK + 9)       // next 9: biasCat (2176 floats)
#define PB_TOT  (PB_BIAS + 1)      // last: zero colsum/colsq
__global__ void prep(const float* __restrict__ features,
                     const float* __restrict__ Wp, const float* __restrict__ Wf,
                     const float* __restrict__ Wqk,
                     const float* __restrict__ bp, const float* __restrict__ bfc,
                     unsigned short* __restrict__ featC,
                     unsigned short* __restrict__ WcatC,
                     unsigned short* __restrict__ WqkC,
                     float* __restrict__ biasCat,
                     float* __restrict__ stats) {
  int b = blockIdx.x;
  if (b < PB_FEAT) {
    int t = b * 256 + threadIdx.x;
    const float4* s = (const float4*)features + 2 * (size_t)t;
    *((bhalf8_t*)featC + t) = cvt8(s[0], s[1]);
  } else if (b < PB_WCAT) {
    int row = b - PB_FEAT;
    int c8 = threadIdx.x * 8;
    const float* src = nullptr;
    if (row < 2048) src = Wp + (size_t)row * FDIM + c8;
    else if (row < 2048 + NCLS) src = Wf + (size_t)(row - 2048) * FDIM + c8;
    bhalf8_t o = {0,0,0,0,0,0,0,0};
    if (src) o = cvt8(*(const float4*)src, *(const float4*)(src + 4));
    *(bhalf8_t*)(WcatC + (size_t)row * FDIM + c8) = o;
  } else if (b < PB_WQK) {
    int t = (b - PB_WCAT) * 256 + threadIdx.x;
    const float4* s = (const float4*)Wqk + 2 * (size_t)t;
    *((bhalf8_t*)WqkC + t) = cvt8(s[0], s[1]);
  } else if (b < PB_BIAS) {
    int i = (b - PB_WQK) * 256 + threadIdx.x;
    if (i < NCAT)
      biasCat[i] = (i < 2048) ? bp[i] : ((i < 2048 + NCLS) ? bfc[i - 2048] : 0.f);
  } else {
    float4 z = {0.f, 0.f, 0.f, 0.f};
#pragma unroll
    for (int i = 0; i < 4; ++i)
      ((float4*)stats)[threadIdx.x * 4 + i] = z;   // 4096 floats = colsum+colsq
  }
}

// ---------------- MFMA GEMM: C[M,N] = A[M,K] * Bw[N,K]^T (+bias[col]) ----------------
// VERBATIM R1 kernel (80 VGPR, 173us, MfmaUtil 38). R2-R5 measured: ANY added
// epilogue structure (bf16 stores, fused stats, logits branch/early-return)
// inflates VGPR 80->92->104, dropping waves/SIMD 6->4 and costing ~20-25%.
// Keep this epilogue branch-free and uniform: one fp32 C array, nullable bias.
__global__ __launch_bounds__(256) void gemm_bt(
    const unsigned short* __restrict__ A, const unsigned short* __restrict__ Bw,
    const float* __restrict__ bias, float* __restrict__ C,
    int K, int lda, int ldb, int ldc)
{
  __shared__ unsigned short lA[128 * 64];
  __shared__ unsigned short lB[128 * 64];
  const int tid = threadIdx.x;
  const int lane = tid & 63, wv = tid >> 6;
  const int m = lane & 15, quad = lane >> 4;
  const size_t rowBase = (size_t)blockIdx.x * 128;
  const size_t colBase = (size_t)blockIdx.y * 128;
  const int m0 = (wv >> 1) * 64, n0 = (wv & 1) * 64;

  f32x4_t acc[4][4];
#pragma unroll
  for (int i = 0; i < 4; ++i)
#pragma unroll
    for (int j = 0; j < 4; ++j) acc[i][j] = (f32x4_t){0.f, 0.f, 0.f, 0.f};

  int sS[4];                 // 16B slot index in LDS tile
  size_t gA[4], gB[4];       // element offsets of the staged chunk
#pragma unroll
  for (int i = 0; i < 4; ++i) {
    int s = ((i * 4 + wv) << 6) + lane;   // [0,1024): 4 issues x 4 waves x 64 lanes
    int r = s >> 3, qp = s & 7;
    int q = qp ^ (r & 7);                 // global k-chunk held at slot qp
    sS[i] = s;
    gA[i] = (rowBase + r) * (size_t)lda + q * 8;
    gB[i] = (colBase + r) * (size_t)ldb + q * 8;
  }

  for (int kb = 0; kb < K; kb += 64) {
#pragma unroll
    for (int i = 0; i < 4; ++i) {
      gl_lds16(A + gA[i] + kb, &lA[sS[i] * 8]);
      gl_lds16(Bw + gB[i] + kb, &lB[sS[i] * 8]);
    }
    __syncthreads();   // drains vmcnt before barrier
#pragma unroll
    for (int ks = 0; ks < 2; ++ks) {
      const int qc = ks * 4 + quad;       // k-chunk this lane's fragment needs
      bhalf8_t af[4], bf[4];
#pragma unroll
      for (int mi = 0; mi < 4; ++mi) {
        int r = m0 + mi * 16 + m;
        af[mi] = *(const bhalf8_t*)&lA[(r * 8 + (qc ^ (r & 7))) * 8];
      }
#pragma unroll
      for (int ni = 0; ni < 4; ++ni) {
        int r = n0 + ni * 16 + m;
        bf[ni] = *(const bhalf8_t*)&lB[(r * 8 + (qc ^ (r & 7))) * 8];
      }
#pragma unroll
      for (int mi = 0; mi < 4; ++mi)
#pragma unroll
        for (int ni = 0; ni < 4; ++ni)
          acc[mi][ni] = __builtin_amdgcn_mfma_f32_16x16x32_bf16(af[mi], bf[ni], acc[mi][ni], 0, 0, 0);
    }
    __syncthreads();
  }

  // epilogue: C/D layout col = lane&15, row = quad*4 + reg
#pragma unroll
  for (int ni = 0; ni < 4; ++ni) {
    size_t gcol = colBase + n0 + ni * 16 + m;
    float bv = bias ? bias[gcol] : 0.f;
#pragma unroll
    for (int mi = 0; mi < 4; ++mi) {
      size_t grow = rowBase + m0 + mi * 16 + quad * 4;
#pragma unroll
      for (int r = 0; r < 4; ++r)
        C[(grow + r) * (size_t)ldc + gcol] = acc[mi][ni][r] + bv;
    }
  }
}

// ---------------- BatchNorm stats (fp32 hcat ld=NCAT, 8 cols/thread, 64 row-blocks) --
__global__ void bn_stats(const float* __restrict__ h,
                         float* __restrict__ cs, float* __restrict__ cq) {
  int c8 = threadIdx.x * 8;            // col group [0, 2048)
  int r0 = blockIdx.x * 256;           // gridDim.x = 64
  float s[8] = {0,0,0,0,0,0,0,0}, q[8] = {0,0,0,0,0,0,0,0};
  for (int r = 0; r < 256; ++r) {
    const float* p = h + (size_t)(r0 + r) * NCAT + c8;
    float4 a = *(const float4*)p, b = *(const float4*)(p + 4);
    float v[8] = {a.x, a.y, a.z, a.w, b.x, b.y, b.z, b.w};
#pragma unroll
    for (int j = 0; j < 8; ++j) { s[j] += v[j]; q[j] += v[j] * v[j]; }
  }
#pragma unroll
  for (int j = 0; j < 8; ++j) {
    atomicAdd(&cs[c8 + j], s[j]);
    atomicAdd(&cq[c8 + j], q[j]);
  }
}

// ---------------- BatchNorm finalize+apply: fp32 hcat -> bf16 hb [B,FDIM] ------------
__global__ void bn_apply(const float* __restrict__ h, unsigned short* __restrict__ hb,
                         const float* __restrict__ cs, const float* __restrict__ cq,
                         const float* __restrict__ g, const float* __restrict__ bt) {
  int t = blockIdx.x * 256 + threadIdx.x;   // grid 16384 -> t < 4194304
  int row = t >> 8;
  int c8 = (t & 255) << 3;
  const float inv = 1.f / (float)BROWS;
  float sc[8], sh[8];
#pragma unroll
  for (int j = 0; j < 8; ++j) {
    int c = c8 + j;
    float mu = cs[c] * inv;
    float var = cq[c] * inv - mu * mu;
    float s = g[c] * rsqrtf(var + 1e-5f);
    sc[j] = s;
    sh[j] = bt[c] - mu * s;
  }
  const float* p = h + (size_t)row * NCAT + c8;
  float4 a = *(const float4*)p, b = *(const float4*)(p + 4);
  float v[8] = {a.x, a.y, a.z, a.w, b.x, b.y, b.z, b.w};
  bhalf8_t o;
#pragma unroll
  for (int j = 0; j < 8; ++j)
    o[j] = f2bf(fmaxf(v[j] * sc[j] + sh[j], 0.f));
  *(bhalf8_t*)(hb + (size_t)row * FDIM + c8) = o;
}

// ---------------- attention epilogue: one wave per row (fp32 qk, logits in hcat) -----
// attn = q k^T (14x14, K=64) via 16x16 MFMA chain; diag subtract, max-|.| normalize,
// corr = attn @ sigmoid(logits); out = logits + gamma*corr.
__global__ __launch_bounds__(256) void attn_ep(
    const float* __restrict__ qk, const float* __restrict__ hcat,
    const float* __restrict__ gamma, float* __restrict__ out)
{
  const int lane = threadIdx.x & 63;
  const int wv = threadIdx.x >> 6;
  const int b = blockIdx.x * 4 + wv;
  const int m = lane & 15, quad = lane >> 4;
  const float* qrow = qk + (size_t)b * QKN;
  f32x4_t acc = (f32x4_t){0.f, 0.f, 0.f, 0.f};
#pragma unroll
  for (int ks = 0; ks < 2; ++ks) {
    bhalf8_t af = {0,0,0,0,0,0,0,0}, bf = {0,0,0,0,0,0,0,0};
    if (m < NCLS) {
      const float* qa = qrow + m * 64 + ks * 32 + quad * 8;  // q[b][m][k..k+8)
      af = cvt8(*(const float4*)qa,         *(const float4*)(qa + 4));
      bf = cvt8(*(const float4*)(qa + 896), *(const float4*)(qa + 900));  // k[b][m][...]
    }
    acc = __builtin_amdgcn_mfma_f32_16x16x32_bf16(af, bf, acc, 0, 0, 0);
  }
  // acc[r] = attn[c = quad*4+r][e = m]
  float logit_e = (m < NCLS) ? hcat[(size_t)b * NCAT + 2048 + m] : 0.f;
  float sig = 1.f / (1.f + __expf(-logit_e));
  float corr[4];
#pragma unroll
  for (int r = 0; r < 4; ++r) {
    int c = quad * 4 + r;
    float diag = __shfl(acc[r], (lane & 48) + c, 64);  // attn[c][c] lives in same 16-lane group
    float a = acc[r] - diag;
    float av = (m < NCLS) ? fabsf(a) : 0.f;
    av = fmaxf(av, __shfl_xor(av, 1, 64));
    av = fmaxf(av, __shfl_xor(av, 2, 64));
    av = fmaxf(av, __shfl_xor(av, 4, 64));
    av = fmaxf(av, __shfl_xor(av, 8, 64));
    float v = (m < NCLS) ? (a / av) * sig : 0.f;
    v += __shfl_xor(v, 1, 64);
    v += __shfl_xor(v, 2, 64);
    v += __shfl_xor(v, 4, 64);
    v += __shfl_xor(v, 8, 64);
    corr[r] = v;
  }
  if (m == 0) {
#pragma unroll
    for (int r = 0; r < 4; ++r) {
      int c = quad * 4 + r;
      if (c < NCLS) {
        float lc = hcat[(size_t)b * NCAT + 2048 + c];
        out[(size_t)b * NCLS + c] = lc + gamma[c] * corr[r];
      }
    }
  }
}

// ---------------- launch ----------------

extern "C" void kernel_launch(void* const* d_in, const int* in_sizes, int n_in,
                              void* d_out, int out_size, void* d_ws, size_t ws_size,
                              hipStream_t stream) {
  const float* features = (const float*)d_in[0];
  const float* W_proj   = (const float*)d_in[1];
  const float* b_proj   = (const float*)d_in[2];
  const float* bn_gamma = (const float*)d_in[3];
  const float* bn_beta  = (const float*)d_in[4];
  const float* W_qk     = (const float*)d_in[5];
  const float* gamma    = (const float*)d_in[6];
  const float* W_fc     = (const float*)d_in[7];
  const float* b_fc     = (const float*)d_in[8];
  float* out = (float*)d_out;

  char* ws = (char*)d_ws;
  unsigned short* featC   = (unsigned short*)ws;                 //  67,108,864 B
  unsigned short* WcatC   = (unsigned short*)(ws + 67108864);    //   8,912,896 B
  unsigned short* WqkC    = (unsigned short*)(ws + 76021760);    //   7,340,032 B
  float*          biasCat = (float*)(ws + 83361792);             //      16,384 B (8704 used)
  float*          hcat    = (float*)(ws + 83378176);             // 142,606,336 B (fp32, incl logits cols)
  float*          qkF     = (float*)(ws + 225984512);            // 117,440,512 B (fp32 qk)
  float*          colsum  = (float*)(ws + 343425024);            //       8,192 B
  float*          colsq   = (float*)(ws + 343433216);            //       8,192 B (tot 343,441,408)
  unsigned short* hb = featC;   // bf16 h: featC dead after GEMM1

  // fused prep: casts + W_cat + bias concat + stats zeroing (one launch)
  prep<<<PB_TOT, 256, 0, stream>>>(features, W_proj, W_fc, W_qk, b_proj, b_fc,
                                   featC, WcatC, WqkC, biasCat, colsum);

  // GEMM1: fp32 hcat[B,2176] = features @ [W_proj; W_fc; 0]^T + biasCat
  gemm_bt<<<dim3(BROWS / 128, NCAT / 128), 256, 0, stream>>>(
      featC, WcatC, biasCat, hcat, FDIM, FDIM, FDIM, NCAT);

  // BN stats over fp32 hcat cols [0,2048)
  bn_stats<<<64, 256, 0, stream>>>(hcat, colsum, colsq);

  // BN finalize+apply (relu): fp32 hcat -> bf16 hb (overwrites dead featC)
  bn_apply<<<16384, 256, 0, stream>>>(hcat, hb, colsum, colsq, bn_gamma, bn_beta);

  // GEMM2: fp32 qk[B,1792] = h @ W_qk^T
  gemm_bt<<<dim3(BROWS / 128, QKN / 128), 256, 0, stream>>>(
      hb, WqkC, nullptr, qkF, FDIM, FDIM, FDIM, QKN);

  // attention epilogue (one wave per row)
  attn_ep<<<BROWS / 4, 256, 0, stream>>>(qkF, hcat, gamma, out);
}

// Round 7
// 637.571 us; speedup vs baseline: 1.0377x; 1.0163x over previous
//
#include <hip/hip_runtime.h>
#include <stdint.h>

// Problem constants
#define BROWS 16384
#define FDIM  2048
#define NCLS  14
#define ADIM  64
#define NCAT  2176   // 2048 (W_proj) + 14 (W_fc) + 114 zero pad -> 17 tiles of 128
#define QKN   1792   // 2*C*D

typedef __attribute__((ext_vector_type(8))) short bhalf8_t;   // 8 bf16 (4 VGPRs)
typedef __attribute__((ext_vector_type(4))) float f32x4_t;    // MFMA C/D frag

__device__ __forceinline__ unsigned short f2bf(float f) {
  unsigned int u = __builtin_bit_cast(unsigned int, f);
  u += 0x7fffu + ((u >> 16) & 1u);      // RNE
  return (unsigned short)(u >> 16);
}

__device__ __forceinline__ void gl_lds16(const void* g, void* l) {
  __builtin_amdgcn_global_load_lds(
      (const __attribute__((address_space(1))) unsigned int*)g,
      (__attribute__((address_space(3))) unsigned int*)l, 16, 0, 0);
}

__device__ __forceinline__ bhalf8_t cvt8(float4 a, float4 b) {
  bhalf8_t o;
  o[0] = f2bf(a.x); o[1] = f2bf(a.y); o[2] = f2bf(a.z); o[3] = f2bf(a.w);
  o[4] = f2bf(b.x); o[5] = f2bf(b.y); o[6] = f2bf(b.z); o[7] = f2bf(b.w);
  return o;
}

// ---------------- fused prep: feature cast | W_cat build | W_qk cast | bias | zero ----
#define PB_FEAT 16384              // blocks 0..16383: features -> bf16 (8/thread)
#define PB_WCAT (PB_FEAT + NCAT)   // next 2176: W_cat rows
#define PB_WQK  (PB_WCAT + 1792)   // next 1792: W_qk cast
#define PB_BIAS (PB_WQK + 9)       // next 9: biasCat (2176 floats)
#define PB_TOT  (PB_BIAS + 1)      // last: zero colsum/colsq
__global__ void prep(const float* __restrict__ features,
                     const float* __restrict__ Wp, const float* __restrict__ Wf,
                     const float* __restrict__ Wqk,
                     const float* __restrict__ bp, const float* __restrict__ bfc,
                     unsigned short* __restrict__ featC,
                     unsigned short* __restrict__ WcatC,
                     unsigned short* __restrict__ WqkC,
                     float* __restrict__ biasCat,
                     float* __restrict__ stats) {
  int b = blockIdx.x;
  if (b < PB_FEAT) {
    int t = b * 256 + threadIdx.x;
    const float4* s = (const float4*)features + 2 * (size_t)t;
    *((bhalf8_t*)featC + t) = cvt8(s[0], s[1]);
  } else if (b < PB_WCAT) {
    int row = b - PB_FEAT;
    int c8 = threadIdx.x * 8;
    const float* src = nullptr;
    if (row < 2048) src = Wp + (size_t)row * FDIM + c8;
    else if (row < 2048 + NCLS) src = Wf + (size_t)(row - 2048) * FDIM + c8;
    bhalf8_t o = {0,0,0,0,0,0,0,0};
    if (src) o = cvt8(*(const float4*)src, *(const float4*)(src + 4));
    *(bhalf8_t*)(WcatC + (size_t)row * FDIM + c8) = o;
  } else if (b < PB_WQK) {
    int t = (b - PB_WCAT) * 256 + threadIdx.x;
    const float4* s = (const float4*)Wqk + 2 * (size_t)t;
    *((bhalf8_t*)WqkC + t) = cvt8(s[0], s[1]);
  } else if (b < PB_BIAS) {
    int i = (b - PB_WQK) * 256 + threadIdx.x;
    if (i < NCAT)
      biasCat[i] = (i < 2048) ? bp[i] : ((i < 2048 + NCLS) ? bfc[i - 2048] : 0.f);
  } else {
    float4 z = {0.f, 0.f, 0.f, 0.f};
#pragma unroll
    for (int i = 0; i < 4; ++i)
      ((float4*)stats)[threadIdx.x * 4 + i] = z;   // 4096 floats = colsum+colsq
  }
}

// ---------------- MFMA GEMM: C[M,N] = A[M,K] * Bw[N,K]^T (+bias[col]) ----------------
// R1 kernel (80 VGPR, MfmaUtil 38). R2-R5 measured: ANY added epilogue structure
// (bf16 stores, fused stats, logits branch/early-return) inflates VGPR 80->92->104,
// dropping waves/SIMD 6->4 and costing ~20-25%. Keep the epilogue branch-free.
// R7: 1D grid + 32-row-tile supergroup swizzle (SGPR-only math) — co-resident blocks
// cover a 32-row x all-col window (A 16.8 MB + B 8.9 MB fits L2 aggregate), cutting
// the measured 3.8x A re-fetch (FETCH 270 MB vs 76 MB ideal @ grid(128,17)).
__global__ __launch_bounds__(256) void gemm_bt(
    const unsigned short* __restrict__ A, const unsigned short* __restrict__ Bw,
    const float* __restrict__ bias, float* __restrict__ C,
    int K, int lda, int ldb, int ldc, int ncol)
{
  __shared__ unsigned short lA[128 * 64];
  __shared__ unsigned short lB[128 * 64];
  const int tid = threadIdx.x;
  const int lane = tid & 63, wv = tid >> 6;
  const int m = lane & 15, quad = lane >> 4;
  // supergroup swizzle: bx -> (rowTile, colTile)
  const int bx = blockIdx.x;
  const int grp = bx >> 5;                       // /32
  const int rowT = (bx & 31) + ((grp / ncol) << 5);
  const int colT = grp % ncol;
  const size_t rowBase = (size_t)rowT * 128;
  const size_t colBase = (size_t)colT * 128;
  const int m0 = (wv >> 1) * 64, n0 = (wv & 1) * 64;

  f32x4_t acc[4][4];
#pragma unroll
  for (int i = 0; i < 4; ++i)
#pragma unroll
    for (int j = 0; j < 4; ++j) acc[i][j] = (f32x4_t){0.f, 0.f, 0.f, 0.f};

  int sS[4];                 // 16B slot index in LDS tile
  size_t gA[4], gB[4];       // element offsets of the staged chunk
#pragma unroll
  for (int i = 0; i < 4; ++i) {
    int s = ((i * 4 + wv) << 6) + lane;   // [0,1024): 4 issues x 4 waves x 64 lanes
    int r = s >> 3, qp = s & 7;
    int q = qp ^ (r & 7);                 // global k-chunk held at slot qp
    sS[i] = s;
    gA[i] = (rowBase + r) * (size_t)lda + q * 8;
    gB[i] = (colBase + r) * (size_t)ldb + q * 8;
  }

  for (int kb = 0; kb < K; kb += 64) {
#pragma unroll
    for (int i = 0; i < 4; ++i) {
      gl_lds16(A + gA[i] + kb, &lA[sS[i] * 8]);
      gl_lds16(Bw + gB[i] + kb, &lB[sS[i] * 8]);
    }
    __syncthreads();   // drains vmcnt before barrier
#pragma unroll
    for (int ks = 0; ks < 2; ++ks) {
      const int qc = ks * 4 + quad;       // k-chunk this lane's fragment needs
      bhalf8_t af[4], bf[4];
#pragma unroll
      for (int mi = 0; mi < 4; ++mi) {
        int r = m0 + mi * 16 + m;
        af[mi] = *(const bhalf8_t*)&lA[(r * 8 + (qc ^ (r & 7))) * 8];
      }
#pragma unroll
      for (int ni = 0; ni < 4; ++ni) {
        int r = n0 + ni * 16 + m;
        bf[ni] = *(const bhalf8_t*)&lB[(r * 8 + (qc ^ (r & 7))) * 8];
      }
#pragma unroll
      for (int mi = 0; mi < 4; ++mi)
#pragma unroll
        for (int ni = 0; ni < 4; ++ni)
          acc[mi][ni] = __builtin_amdgcn_mfma_f32_16x16x32_bf16(af[mi], bf[ni], acc[mi][ni], 0, 0, 0);
    }
    __syncthreads();
  }

  // epilogue: C/D layout col = lane&15, row = quad*4 + reg
#pragma unroll
  for (int ni = 0; ni < 4; ++ni) {
    size_t gcol = colBase + n0 + ni * 16 + m;
    float bv = bias ? bias[gcol] : 0.f;
#pragma unroll
    for (int mi = 0; mi < 4; ++mi) {
      size_t grow = rowBase + m0 + mi * 16 + quad * 4;
#pragma unroll
      for (int r = 0; r < 4; ++r)
        C[(grow + r) * (size_t)ldc + gcol] = acc[mi][ni][r] + bv;
    }
  }
}

// ---------------- BatchNorm stats (fp32 hcat ld=NCAT, 8 cols/thread) -----------------
// 256 blocks x 64 rows: all 256 CUs active (R4-R6 regression: 64 blocks used only
// 64 CUs -> ~85us for a 134 MB pass; atomics are cheap, CU parallelism is not).
__global__ void bn_stats(const float* __restrict__ h,
                         float* __restrict__ cs, float* __restrict__ cq) {
  int c8 = threadIdx.x * 8;            // col group [0, 2048)
  int r0 = blockIdx.x * 64;            // gridDim.x = 256
  float s[8] = {0,0,0,0,0,0,0,0}, q[8] = {0,0,0,0,0,0,0,0};
  for (int r = 0; r < 64; ++r) {
    const float* p = h + (size_t)(r0 + r) * NCAT + c8;
    float4 a = *(const float4*)p, b = *(const float4*)(p + 4);
    float v[8] = {a.x, a.y, a.z, a.w, b.x, b.y, b.z, b.w};
#pragma unroll
    for (int j = 0; j < 8; ++j) { s[j] += v[j]; q[j] += v[j] * v[j]; }
  }
#pragma unroll
  for (int j = 0; j < 8; ++j) {
    atomicAdd(&cs[c8 + j], s[j]);
    atomicAdd(&cq[c8 + j], q[j]);
  }
}

// ---------------- BatchNorm finalize+apply: fp32 hcat -> bf16 hb [B,FDIM] ------------
__global__ void bn_apply(const float* __restrict__ h, unsigned short* __restrict__ hb,
                         const float* __restrict__ cs, const float* __restrict__ cq,
                         const float* __restrict__ g, const float* __restrict__ bt) {
  int t = blockIdx.x * 256 + threadIdx.x;   // grid 16384 -> t < 4194304
  int row = t >> 8;
  int c8 = (t & 255) << 3;
  const float inv = 1.f / (float)BROWS;
  float sc[8], sh[8];
#pragma unroll
  for (int j = 0; j < 8; ++j) {
    int c = c8 + j;
    float mu = cs[c] * inv;
    float var = cq[c] * inv - mu * mu;
    float s = g[c] * rsqrtf(var + 1e-5f);
    sc[j] = s;
    sh[j] = bt[c] - mu * s;
  }
  const float* p = h + (size_t)row * NCAT + c8;
  float4 a = *(const float4*)p, b = *(const float4*)(p + 4);
  float v[8] = {a.x, a.y, a.z, a.w, b.x, b.y, b.z, b.w};
  bhalf8_t o;
#pragma unroll
  for (int j = 0; j < 8; ++j)
    o[j] = f2bf(fmaxf(v[j] * sc[j] + sh[j], 0.f));
  *(bhalf8_t*)(hb + (size_t)row * FDIM + c8) = o;
}

// ---------------- attention epilogue: one wave per row (fp32 qk, logits in hcat) -----
// attn = q k^T (14x14, K=64) via 16x16 MFMA chain; diag subtract, max-|.| normalize,
// corr = attn @ sigmoid(logits); out = logits + gamma*corr.
__global__ __launch_bounds__(256) void attn_ep(
    const float* __restrict__ qk, const float* __restrict__ hcat,
    const float* __restrict__ gamma, float* __restrict__ out)
{
  const int lane = threadIdx.x & 63;
  const int wv = threadIdx.x >> 6;
  const int b = blockIdx.x * 4 + wv;
  const int m = lane & 15, quad = lane >> 4;
  const float* qrow = qk + (size_t)b * QKN;
  f32x4_t acc = (f32x4_t){0.f, 0.f, 0.f, 0.f};
#pragma unroll
  for (int ks = 0; ks < 2; ++ks) {
    bhalf8_t af = {0,0,0,0,0,0,0,0}, bf = {0,0,0,0,0,0,0,0};
    if (m < NCLS) {
      const float* qa = qrow + m * 64 + ks * 32 + quad * 8;  // q[b][m][k..k+8)
      af = cvt8(*(const float4*)qa,         *(const float4*)(qa + 4));
      bf = cvt8(*(const float4*)(qa + 896), *(const float4*)(qa + 900));  // k[b][m][...]
    }
    acc = __builtin_amdgcn_mfma_f32_16x16x32_bf16(af, bf, acc, 0, 0, 0);
  }
  // acc[r] = attn[c = quad*4+r][e = m]
  float logit_e = (m < NCLS) ? hcat[(size_t)b * NCAT + 2048 + m] : 0.f;
  float sig = 1.f / (1.f + __expf(-logit_e));
  float corr[4];
#pragma unroll
  for (int r = 0; r < 4; ++r) {
    int c = quad * 4 + r;
    float diag = __shfl(acc[r], (lane & 48) + c, 64);  // attn[c][c] lives in same 16-lane group
    float a = acc[r] - diag;
    float av = (m < NCLS) ? fabsf(a) : 0.f;
    av = fmaxf(av, __shfl_xor(av, 1, 64));
    av = fmaxf(av, __shfl_xor(av, 2, 64));
    av = fmaxf(av, __shfl_xor(av, 4, 64));
    av = fmaxf(av, __shfl_xor(av, 8, 64));
    float v = (m < NCLS) ? (a / av) * sig : 0.f;
    v += __shfl_xor(v, 1, 64);
    v += __shfl_xor(v, 2, 64);
    v += __shfl_xor(v, 4, 64);
    v += __shfl_xor(v, 8, 64);
    corr[r] = v;
  }
  if (m == 0) {
#pragma unroll
    for (int r = 0; r < 4; ++r) {
      int c = quad * 4 + r;
      if (c < NCLS) {
        float lc = hcat[(size_t)b * NCAT + 2048 + c];
        out[(size_t)b * NCLS + c] = lc + gamma[c] * corr[r];
      }
    }
  }
}

// ---------------- launch ----------------

extern "C" void kernel_launch(void* const* d_in, const int* in_sizes, int n_in,
                              void* d_out, int out_size, void* d_ws, size_t ws_size,
                              hipStream_t stream) {
  const float* features = (const float*)d_in[0];
  const float* W_proj   = (const float*)d_in[1];
  const float* b_proj   = (const float*)d_in[2];
  const float* bn_gamma = (const float*)d_in[3];
  const float* bn_beta  = (const float*)d_in[4];
  const float* W_qk     = (const float*)d_in[5];
  const float* gamma    = (const float*)d_in[6];
  const float* W_fc     = (const float*)d_in[7];
  const float* b_fc     = (const float*)d_in[8];
  float* out = (float*)d_out;

  char* ws = (char*)d_ws;
  unsigned short* featC   = (unsigned short*)ws;                 //  67,108,864 B
  unsigned short* WcatC   = (unsigned short*)(ws + 67108864);    //   8,912,896 B
  unsigned short* WqkC    = (unsigned short*)(ws + 76021760);    //   7,340,032 B
  float*          biasCat = (float*)(ws + 83361792);             //      16,384 B (8704 used)
  float*          hcat    = (float*)(ws + 83378176);             // 142,606,336 B (fp32, incl logits cols)
  float*          qkF     = (float*)(ws + 225984512);            // 117,440,512 B (fp32 qk)
  float*          colsum  = (float*)(ws + 343425024);            //       8,192 B
  float*          colsq   = (float*)(ws + 343433216);            //       8,192 B (tot 343,441,408)
  unsigned short* hb = featC;   // bf16 h: featC dead after GEMM1

  // fused prep: casts + W_cat + bias concat + stats zeroing (one launch)
  prep<<<PB_TOT, 256, 0, stream>>>(features, W_proj, W_fc, W_qk, b_proj, b_fc,
                                   featC, WcatC, WqkC, biasCat, colsum);

  // GEMM1: fp32 hcat[B,2176] = features @ [W_proj; W_fc; 0]^T + biasCat
  gemm_bt<<<128 * (NCAT / 128), 256, 0, stream>>>(
      featC, WcatC, biasCat, hcat, FDIM, FDIM, FDIM, NCAT, NCAT / 128);

  // BN stats over fp32 hcat cols [0,2048)
  bn_stats<<<256, 256, 0, stream>>>(hcat, colsum, colsq);

  // BN finalize+apply (relu): fp32 hcat -> bf16 hb (overwrites dead featC)
  bn_apply<<<16384, 256, 0, stream>>>(hcat, hb, colsum, colsq, bn_gamma, bn_beta);

  // GEMM2: fp32 qk[B,1792] = h @ W_qk^T
  gemm_bt<<<128 * (QKN / 128), 256, 0, stream>>>(
      hb, WqkC, nullptr, qkF, FDIM, FDIM, FDIM, QKN, QKN / 128);

  // attention epilogue (one wave per row)
  attn_ep<<<BROWS / 4, 256, 0, stream>>>(qkF, hcat, gamma, out);
}